// Round 15
// baseline (202.532 us; speedup 1.0000x reference)
//
#include <hip/hip_runtime.h>

// db2 filters, pre-flipped (cross-correlation form used by ptwt)
#define F_LO0 0.4829629131445341f
#define F_LO1 0.8365163037378079f
#define F_LO2 0.22414386804185735f
#define F_LO3 (-0.12940952255092145f)
#define F_HI0 (-0.12940952255092145f)
#define F_HI1 (-0.22414386804185735f)
#define F_HI2 0.8365163037378079f
#define F_HI3 (-0.4829629131445341f)

__device__ __forceinline__ int reflect_idx(int r, int n) {
    r = (r < 0) ? -r : r;
    r = (r >= n) ? 2 * n - 2 - r : r;
    return r;
}

// vertical 4-tap filter on float4 lanes (4 columns at once)
__device__ __forceinline__ float4 vfilt(const float4 a, const float4 b,
                                        const float4 c, const float4 d,
                                        float c0, float c1, float c2, float c3) {
    return make_float4(c0 * a.x + c1 * b.x + c2 * c.x + c3 * d.x,
                       c0 * a.y + c1 * b.y + c2 * c.y + c3 * d.y,
                       c0 * a.z + c1 * b.z + c2 * c.z + c3 * d.z,
                       c0 * a.w + c1 * b.w + c2 * c.w + c3 * d.w);
}

// Fused 3-level WPT + weighted squared-sum.
// R15: LDS-pipe isolation experiment. v1 register-blocked 2 rows/thread
// (12 b128 reads vs 16 per 2 rows, -25%); L3 register-blocked 2x2 outputs/
// thread (18 b64 reads per 16 outputs vs 32, -44%, h3 rows reused in regs).
// Everything else (front end, layout, barriers, residency) = R14.
__global__ void __launch_bounds__(512, 6) k_wpt_fused(
    const float* __restrict__ p, const float* __restrict__ t,
    float* __restrict__ partial) {
    constexpr int N0 = 512, N1 = 257, N2 = 130, N3 = 66;

    __shared__ __align__(16) float sA[6080];  // L1 bands 4 x 38 rows x stride 40
    __shared__ __align__(16) float sB[6240];  // h1 lo/hi 78x40; reused as L2 [16][324]
    __shared__ float wsum[8];

    // XCD-chunked swizzle: 15552 = 8 * 1944 (bijective)
    int bid = blockIdx.x;
    int swz = (bid & 7) * (int)(gridDim.x >> 3) + (bid >> 3);
    int img = swz / 81;
    int tt = swz - img * 81;
    int TA = (tt / 9) * 8;
    int TB = (tt % 9) * 8;

    const int tid = threadIdx.x;
    const size_t ibase = (size_t)img * (N0 * N0);

    const int O0r = 8 * TA - 14, O0c = 8 * TB - 16;  // col origin 16B-aligned
    const int O1r = 4 * TA - 6, O1c = 4 * TB - 6;
    const int O2r = 2 * TA - 2, O2c = 2 * TB - 2;
    const bool edge = (TA == 0) || (TA == 64) || (TB == 0) || (TB == 64);

    // ---- h1 from global (R10/R14 verbatim): 390 threads = (row 0..77, k 0..4) ----
    if (tid < 390) {
        unsigned ru = (unsigned)tid / 5u;
        const int r = (int)ru;
        const int k = tid - (int)(5u * ru);
        const int grr = reflect_idx(O0r + r, N0);
        const float* __restrict__ prow = p + ibase + (size_t)grr * N0;
        const float* __restrict__ trow = t + ibase + (size_t)grr * N0;
        const int gc0 = O0c + 16 * k;
        float v[20];
        if ((unsigned)gc0 <= 492u) {
#pragma unroll
            for (int q = 0; q < 5; ++q) {
                const float4 pv = *(const float4*)(prow + gc0 + 4 * q);
                const float4 tv = *(const float4*)(trow + gc0 + 4 * q);
                v[4 * q + 0] = pv.x - tv.x;
                v[4 * q + 1] = pv.y - tv.y;
                v[4 * q + 2] = pv.z - tv.z;
                v[4 * q + 3] = pv.w - tv.w;
            }
        } else {
#pragma unroll
            for (int x = 0; x < 20; ++x) {
                int gc = reflect_idx(gc0 + x, N0);
                v[x] = prow[gc] - trow[gc];
            }
        }
        float* dst = sB + r * 40 + 8 * k;
        *(float4*)(dst) = make_float4(
            F_LO0 * v[2] + F_LO1 * v[3] + F_LO2 * v[4] + F_LO3 * v[5],
            F_LO0 * v[4] + F_LO1 * v[5] + F_LO2 * v[6] + F_LO3 * v[7],
            F_LO0 * v[6] + F_LO1 * v[7] + F_LO2 * v[8] + F_LO3 * v[9],
            F_LO0 * v[8] + F_LO1 * v[9] + F_LO2 * v[10] + F_LO3 * v[11]);
        *(float4*)(dst + 4) = make_float4(
            F_LO0 * v[10] + F_LO1 * v[11] + F_LO2 * v[12] + F_LO3 * v[13],
            F_LO0 * v[12] + F_LO1 * v[13] + F_LO2 * v[14] + F_LO3 * v[15],
            F_LO0 * v[14] + F_LO1 * v[15] + F_LO2 * v[16] + F_LO3 * v[17],
            F_LO0 * v[16] + F_LO1 * v[17] + F_LO2 * v[18] + F_LO3 * v[19]);
        *(float4*)(dst + 3120) = make_float4(
            F_HI0 * v[2] + F_HI1 * v[3] + F_HI2 * v[4] + F_HI3 * v[5],
            F_HI0 * v[4] + F_HI1 * v[5] + F_HI2 * v[6] + F_HI3 * v[7],
            F_HI0 * v[6] + F_HI1 * v[7] + F_HI2 * v[8] + F_HI3 * v[9],
            F_HI0 * v[8] + F_HI1 * v[9] + F_HI2 * v[10] + F_HI3 * v[11]);
        *(float4*)(dst + 3124) = make_float4(
            F_HI0 * v[10] + F_HI1 * v[11] + F_HI2 * v[12] + F_HI3 * v[13],
            F_HI0 * v[12] + F_HI1 * v[13] + F_HI2 * v[14] + F_HI3 * v[15],
            F_HI0 * v[14] + F_HI1 * v[15] + F_HI2 * v[16] + F_HI3 * v[17],
            F_HI0 * v[16] + F_HI1 * v[17] + F_HI2 * v[18] + F_HI3 * v[19]);
    }
    __syncthreads();

    // ---- v1 (2-row register blocked): 190 threads = (row-pair rp 0..18, k 0..9).
    //      12 b128 reads -> 2 L1 rows x 4 bands (8 b128 writes). ----
    if (tid < 190) {
        const int rp = tid / 10, k = tid - (tid / 10) * 10;
        const float* blo = sB + (4 * rp) * 40 + 4 * k;
        const float* bhi = blo + 3120;
        float4 L[6], H[6];
#pragma unroll
        for (int j = 0; j < 6; ++j) {
            L[j] = *(const float4*)(blo + 40 * j);
            H[j] = *(const float4*)(bhi + 40 * j);
        }
#pragma unroll
        for (int rr = 0; rr < 2; ++rr) {
            float4 b0 = vfilt(L[2 * rr], L[2 * rr + 1], L[2 * rr + 2], L[2 * rr + 3],
                              F_LO0, F_LO1, F_LO2, F_LO3);
            float4 b1 = vfilt(L[2 * rr], L[2 * rr + 1], L[2 * rr + 2], L[2 * rr + 3],
                              F_HI0, F_HI1, F_HI2, F_HI3);
            float4 b2 = vfilt(H[2 * rr], H[2 * rr + 1], H[2 * rr + 2], H[2 * rr + 3],
                              F_LO0, F_LO1, F_LO2, F_LO3);
            float4 b3 = vfilt(H[2 * rr], H[2 * rr + 1], H[2 * rr + 2], H[2 * rr + 3],
                              F_HI0, F_HI1, F_HI2, F_HI3);
            const int wo = (2 * rp + rr) * 40 + 4 * k;
            *(float4*)(sA + wo) = b0;
            *(float4*)(sA + 1520 + wo) = b1;
            *(float4*)(sA + 3040 + wo) = b2;
            *(float4*)(sA + 4560 + wo) = b3;
        }
    }
    __syncthreads();
    if (edge) {  // patch reflected L1 slots (sources are fixed points: no race)
#pragma unroll
        for (int it = 0; it < 3; ++it) {
            int e = it * 512 + tid;
            if (e < 1444) {
                int lr = e / 38, lc = e - lr * 38;
                int sr = reflect_idx(O1r + lr, N1) - O1r;
                int sc = reflect_idx(O1c + lc, N1) - O1c;
                if ((sr != lr || sc != lc) && (unsigned)sr < 38u && (unsigned)sc < 38u) {
                    int da = lr * 40 + lc;
                    int sa = sr * 40 + sc;
                    sA[da] = sA[sa];
                    sA[1520 + da] = sA[1520 + sa];
                    sA[3040 + da] = sA[3040 + sa];
                    sA[4560 + da] = sA[4560 + sa];
                }
            }
        }
        __syncthreads();
    }

    // ---- L2 (R14 verbatim): 324 threads, one (r2,c2) cell; sB := [16][324] ----
    if (tid < 324) {
        const int r2 = tid / 18, c2 = tid - 18 * (tid / 18);
        const int rb = r2 * 80 + 2 * c2;
#pragma unroll
        for (int b = 0; b < 4; ++b) {
            const float* base = sA + b * 1520 + rb;
            float lo[4], hi[4];
#pragma unroll
            for (int u = 0; u < 4; ++u) {
                float2 a = *(const float2*)(base + u * 40);
                float2 d = *(const float2*)(base + u * 40 + 2);
                lo[u] = F_LO0 * a.x + F_LO1 * a.y + F_LO2 * d.x + F_LO3 * d.y;
                hi[u] = F_HI0 * a.x + F_HI1 * a.y + F_HI2 * d.x + F_HI3 * d.y;
            }
            float* dst = sB + (b * 4) * 324 + tid;
            dst[0]   = F_LO0 * lo[0] + F_LO1 * lo[1] + F_LO2 * lo[2] + F_LO3 * lo[3];
            dst[324] = F_HI0 * lo[0] + F_HI1 * lo[1] + F_HI2 * lo[2] + F_HI3 * lo[3];
            dst[648] = F_LO0 * hi[0] + F_LO1 * hi[1] + F_LO2 * hi[2] + F_LO3 * hi[3];
            dst[972] = F_HI0 * hi[0] + F_HI1 * hi[1] + F_HI2 * hi[2] + F_HI3 * hi[3];
        }
    }
    __syncthreads();
    if (edge) {  // patch reflected L2 slots (full 18x18 tile; sources interior)
        if (tid < 324) {
            const int lr = tid / 18, lc = tid - 18 * (tid / 18);
            int sr = reflect_idx(O2r + lr, N2) - O2r;
            int sc = reflect_idx(O2c + lc, N2) - O2c;
            if ((sr != lr || sc != lc) && (unsigned)sr < 18u && (unsigned)sc < 18u) {
                int d = lr * 18 + lc;
                int s = sr * 18 + sc;
#pragma unroll
                for (int pl = 0; pl < 16; ++pl) sB[pl * 324 + d] = sB[pl * 324 + s];
            }
        }
        __syncthreads();
    }

    // ---- L3 (2x2 register blocked): 256 threads = (plane pl, bi, bj).
    //      18 b64 reads -> h3 rows in regs -> 4 outputs x 4 bands. ----
    float local = 0.f;
    if (tid < 256) {
        const int pl = tid >> 4;
        const int bi = (tid >> 2) & 3, bj = tid & 3;
        const float* base = sB + pl * 324 + (4 * bi) * 18 + 4 * bj;
        float hl[6][2], hh[6][2];
#pragma unroll
        for (int r = 0; r < 6; ++r) {
            float2 a = *(const float2*)(base + r * 18);
            float2 b = *(const float2*)(base + r * 18 + 2);
            float2 c = *(const float2*)(base + r * 18 + 4);
            hl[r][0] = F_LO0 * a.x + F_LO1 * a.y + F_LO2 * b.x + F_LO3 * b.y;
            hl[r][1] = F_LO0 * b.x + F_LO1 * b.y + F_LO2 * c.x + F_LO3 * c.y;
            hh[r][0] = F_HI0 * a.x + F_HI1 * a.y + F_HI2 * b.x + F_HI3 * b.y;
            hh[r][1] = F_HI0 * b.x + F_HI1 * b.y + F_HI2 * c.x + F_HI3 * c.y;
        }
        const float w00 = (pl == 0) ? 0.5f : 1.0f;
#pragma unroll
        for (int du = 0; du < 2; ++du) {
            const bool rok = (TA + 2 * bi + du < N3);
#pragma unroll
            for (int dv = 0; dv < 2; ++dv) {
                if (rok && (TB + 2 * bj + dv < N3)) {
                    float o0 = F_LO0 * hl[2 * du][dv] + F_LO1 * hl[2 * du + 1][dv] +
                               F_LO2 * hl[2 * du + 2][dv] + F_LO3 * hl[2 * du + 3][dv];
                    float o1 = F_HI0 * hl[2 * du][dv] + F_HI1 * hl[2 * du + 1][dv] +
                               F_HI2 * hl[2 * du + 2][dv] + F_HI3 * hl[2 * du + 3][dv];
                    float o2 = F_LO0 * hh[2 * du][dv] + F_LO1 * hh[2 * du + 1][dv] +
                               F_LO2 * hh[2 * du + 2][dv] + F_LO3 * hh[2 * du + 3][dv];
                    float o3 = F_HI0 * hh[2 * du][dv] + F_HI1 * hh[2 * du + 1][dv] +
                               F_HI2 * hh[2 * du + 2][dv] + F_HI3 * hh[2 * du + 3][dv];
                    local += w00 * o0 * o0 + o1 * o1 + o2 * o2 + o3 * o3;
                }
            }
        }
    }

    // block reduction: 8 waves, one plain store per block (no atomic)
#pragma unroll
    for (int o = 32; o > 0; o >>= 1) local += __shfl_down(local, o, 64);
    const int w = tid >> 6;
    if ((tid & 63) == 0) wsum[w] = local;
    __syncthreads();
    if (tid == 0) {
        float ssum = 0.f;
#pragma unroll
        for (int x = 0; x < 8; ++x) ssum += wsum[x];
        partial[blockIdx.x] = ssum;
    }
}

// Final reduction: sum 15552 per-block partials -> out[0]. Single block.
__global__ void __launch_bounds__(1024) k_reduce(const float* __restrict__ part,
                                                 float* __restrict__ out,
                                                 int n4, float inv_den) {
    const int tid = threadIdx.x;
    float s = 0.f;
    const float4* p4 = (const float4*)part;
    for (int i = tid; i < n4; i += 1024) {
        float4 v = p4[i];
        s += v.x + v.y + v.z + v.w;
    }
#pragma unroll
    for (int o = 32; o > 0; o >>= 1) s += __shfl_down(s, o, 64);
    __shared__ float ws_[16];
    int w = tid >> 6;
    if ((tid & 63) == 0) ws_[w] = s;
    __syncthreads();
    if (tid == 0) {
        float tot = 0.f;
#pragma unroll
        for (int i = 0; i < 16; ++i) tot += ws_[i];
        out[0] = tot * inv_den;
    }
}

extern "C" void kernel_launch(void* const* d_in, const int* in_sizes, int n_in,
                              void* d_out, int out_size, void* d_ws, size_t ws_size,
                              hipStream_t stream) {
    const float* preds = (const float*)d_in[0];
    const float* targets = (const float*)d_in[1];
    float* out = (float*)d_out;
    float* partial = (float*)d_ws;  // 15552 floats = 62 KB

    const float inv_den = 1.0f / (192.0f * 66.0f * 66.0f);
    const int nblk = 192 * 9 * 9;  // 15552, divisible by 8

    k_wpt_fused<<<dim3(nblk), dim3(512), 0, stream>>>(preds, targets, partial);
    k_reduce<<<dim3(1), dim3(1024), 0, stream>>>(partial, out, nblk / 4, inv_den);
}